// Round 11
// baseline (167.365 us; speedup 1.0000x reference)
//
#include <hip/hip_runtime.h>
#include <math.h>

#define T_  2048
#define C_  1024
#define HD_ 64

typedef __attribute__((ext_vector_type(8))) short bf16x8;   // 8 bf16 = 4 VGPRs
typedef __attribute__((ext_vector_type(4))) float f32x4;    // MFMA C/D

#define MFMA_BF16(A, B, C) __builtin_amdgcn_mfma_f32_16x16x32_bf16(A, B, C, 0, 0, 0)

// 8 * log2(e): q is pre-scaled so scores live in log2 domain (v_exp_f32 = 2^x)
#define QSCALE 11.54156032711171f

// v_exp_f32 is natively 2^x; HIP has no __exp2f device intrinsic (R5 compile fail)
#define EXP2F(x) __builtin_amdgcn_exp2f(x)

__device__ __forceinline__ short f2bf(float f) {
    union { float f; unsigned u; } v; v.f = f;
    unsigned r = v.u + 0x7fffu + ((v.u >> 16) & 1u);   // RTNE
    return (short)(r >> 16);
}
__device__ __forceinline__ float bf2f(short s) {
    union { float f; unsigned u; } v;
    v.u = ((unsigned)(unsigned short)s) << 16;
    return v.f;
}

// ---------------------------------------------------------------------------
// K0: W[1024][64] fp32 -> wtf in MFMA B-FRAGMENT order (hi/lo planes).
// ---------------------------------------------------------------------------
__global__ __launch_bounds__(256) void prep_w_kernel(
    const float* __restrict__ Wq, const float* __restrict__ Wk,
    const float* __restrict__ Wv, short* __restrict__ wtf)
{
    const int m = blockIdx.y;
    const float* W = (m == 0) ? Wq : (m == 1) ? Wk : Wv;
    const int t = threadIdx.x;
    const int c = blockIdx.x * 64 + (t >> 2);
    const int hg = (t & 3) * 16;
    const int ct = m * 4 + (t & 3);
    const int c0i = c >> 6, kc = (c >> 5) & 1, lq = (c >> 3) & 3, e = c & 7;
    const float4* wp = (const float4*)(W + (size_t)c * HD_ + hg);
    #pragma unroll
    for (int u = 0; u < 4; ++u) {
        float4 f = wp[u];
        float vs[4] = {f.x, f.y, f.z, f.w};
        #pragma unroll
        for (int ei = 0; ei < 4; ++ei) {
            int h16 = u * 4 + ei;              // h & 15
            int L = h16 + 16 * lq;
            short hh = f2bf(vs[ei]);
            short lo = f2bf(vs[ei] - bf2f(hh));
            size_t oh = ((((size_t)(ct * 2 + 0) * 16 + c0i) * 2 + kc) * 64 + L) * 8 + e;
            size_t ol = ((((size_t)(ct * 2 + 1) * 16 + c0i) * 2 + kc) * 64 + L) * 8 + e;
            wtf[oh] = hh;
            wtf[ol] = lo;
        }
    }
}

// ---------------------------------------------------------------------------
// K1: merged QKV projection (R3/R7-proven: 512 blocks x 256 thr, 2/CU,
// double-buffered x LDS, one barrier per step, W direct fragment loads).
// ---------------------------------------------------------------------------
__global__ __launch_bounds__(256) void qkv_proj_kernel(
    const float* __restrict__ x, const short* __restrict__ wtf,
    short* __restrict__ qhp, short* __restrict__ qlp,
    short* __restrict__ khp, short* __restrict__ klp,
    short* __restrict__ vtp)
{
    __shared__ __align__(16) short xh[2][16 * 64], xl[2][16 * 64];  // 2x2 KB each

    const int t = threadIdx.x, L = t & 63, wv = t >> 6;
    const int R0 = blockIdx.x * 16;
    const int ctq = wv;                    // wave's 16-col tile

    f32x4 acc[3];
    #pragma unroll
    for (int j = 0; j < 3; ++j) acc[j] = {0.f, 0.f, 0.f, 0.f};

    const int xrow = t >> 4, xc4 = t & 15;
    const float* xp = x + (size_t)(R0 + xrow) * C_ + xc4 * 4;
    float4 xa;
    auto loadX = [&](int c0) { xa = *(const float4*)(xp + c0); };

    const int c8 = xc4 >> 1, xhalf = xc4 & 1;
    const int slot = xrow * 64 + ((c8 ^ (xrow & 7)) * 8) + xhalf * 4;
    auto stageX = [&](int buf) {
        float vs[4] = {xa.x, xa.y, xa.z, xa.w};
        short4 vh, vl;
        short* vhp = (short*)&vh; short* vlp = (short*)&vl;
        #pragma unroll
        for (int e = 0; e < 4; ++e) {
            short hh = f2bf(vs[e]);
            vhp[e] = hh;
            vlp[e] = f2bf(vs[e] - bf2f(hh));
        }
        *(short4*)&xh[buf][slot] = vh;
        *(short4*)&xl[buf][slot] = vl;
    };

    const size_t lo8 = (size_t)L * 8;
    auto loadWF = [&](int c0i, int kc, bf16x8* w) {
        w[0] = *(const bf16x8*)(wtf + (size_t)((((ctq + 0) * 2 + 0) * 16 + c0i) * 2 + kc) * 512 + lo8);
        w[1] = *(const bf16x8*)(wtf + (size_t)((((ctq + 0) * 2 + 1) * 16 + c0i) * 2 + kc) * 512 + lo8);
        w[2] = *(const bf16x8*)(wtf + (size_t)((((ctq + 4) * 2 + 0) * 16 + c0i) * 2 + kc) * 512 + lo8);
        w[3] = *(const bf16x8*)(wtf + (size_t)((((ctq + 4) * 2 + 1) * 16 + c0i) * 2 + kc) * 512 + lo8);
        w[4] = *(const bf16x8*)(wtf + (size_t)((((ctq + 8) * 2 + 0) * 16 + c0i) * 2 + kc) * 512 + lo8);
    };

    bf16x8 wf0[5], wf1[5];
    const int arow = L & 15;

    loadX(0);
    loadWF(0, 0, wf0);
    stageX(0);
    loadX(64);
    __syncthreads();

    for (int c0i = 0; c0i < 16; ++c0i) {
        const int cur = c0i & 1;
        if (c0i < 15) {
            stageX(cur ^ 1);
            if (c0i < 14) loadX((c0i + 2) * 64);
        }
        loadWF(c0i, 1, wf1);
        {
            int ch = (L >> 4);
            int off = arow * 64 + ((ch ^ (arow & 7)) * 8);
            bf16x8 axh = *(const bf16x8*)&xh[cur][off];
            bf16x8 axl = *(const bf16x8*)&xl[cur][off];
            acc[0] = MFMA_BF16(axl, wf0[0], acc[0]);
            acc[0] = MFMA_BF16(axh, wf0[1], acc[0]);
            acc[0] = MFMA_BF16(axh, wf0[0], acc[0]);
            acc[1] = MFMA_BF16(axl, wf0[2], acc[1]);
            acc[1] = MFMA_BF16(axh, wf0[3], acc[1]);
            acc[1] = MFMA_BF16(axh, wf0[2], acc[1]);
            acc[2] = MFMA_BF16(wf0[4], axh, acc[2]);   // v swapped -> D[h][t]
        }
        if (c0i < 15) loadWF(c0i + 1, 0, wf0);
        {
            int ch = 4 + (L >> 4);
            int off = arow * 64 + ((ch ^ (arow & 7)) * 8);
            bf16x8 axh = *(const bf16x8*)&xh[cur][off];
            bf16x8 axl = *(const bf16x8*)&xl[cur][off];
            acc[0] = MFMA_BF16(axl, wf1[0], acc[0]);
            acc[0] = MFMA_BF16(axh, wf1[1], acc[0]);
            acc[0] = MFMA_BF16(axh, wf1[0], acc[0]);
            acc[1] = MFMA_BF16(axl, wf1[2], acc[1]);
            acc[1] = MFMA_BF16(axh, wf1[3], acc[1]);
            acc[1] = MFMA_BF16(axh, wf1[2], acc[1]);
            acc[2] = MFMA_BF16(wf1[4], axh, acc[2]);
        }
        __syncthreads();
    }

    // ---- epilogue (q scaled into log2 domain: 8*log2(e))
    const int quad = L >> 4;
    #pragma unroll
    for (int r = 0; r < 4; ++r) {
        int row = R0 + quad * 4 + r;
        int h = ctq * 16 + (L & 15);
        float vq = acc[0][r] * QSCALE;
        short hq = f2bf(vq);
        qhp[(size_t)row * HD_ + h] = hq;
        qlp[(size_t)row * HD_ + h] = f2bf(vq - bf2f(hq));
        float vk = acc[1][r];
        short hk = f2bf(vk);
        khp[(size_t)row * HD_ + h] = hk;
        klp[(size_t)row * HD_ + h] = f2bf(vk - bf2f(hk));
        int d = ctq * 16 + quad * 4 + r;
        int tt = R0 + (L & 15);
        int bb = tt >> 11, tl = tt & (T_ - 1);
        vtp[(size_t)(bb * 64 + d) * T_ + tl] = f2bf(acc[2][r]);
    }
}

// ---------------------------------------------------------------------------
// K2: FUSED stats + pv with RECOMPUTE (no score spill). R10 bug fixed:
// denominator was counted 4x (all 4 waves of a col-half read identical es
// rows; dred summed all 8 waves). Now only the dt==0 wave of each half
// contributes, D = dred[0] + dred[1].
// ---------------------------------------------------------------------------
__global__ __launch_bounds__(512) void fused_attn_kernel(
    const short* __restrict__ qhp, const short* __restrict__ qlp,
    const short* __restrict__ khp, const short* __restrict__ klp,
    const short* __restrict__ vtp, float* __restrict__ out)
{
    __shared__ float red[8][16][2];
    __shared__ float msl[16];
    __shared__ __align__(16) float es[16][2][128];   // 16 KB weight bounce
    __shared__ float ored2[8][16][16];               // 8 KB per-wave PV tile
    __shared__ float dred[2][16];                    // per-half row sums

    const int t = threadIdx.x, L = t & 63, wv = t >> 6;
    const int k = blockIdx.x >> 1, half = blockIdx.x & 1;
    const int b = k >> 6, j = k & 63;
    const int p = half ? (127 - j) : j;
    const int T0 = p * 16;
    const int q4 = L >> 4, m16 = L & 15;
    const int cho = q4 * 8;

    // q fragments (rows T0..T0+15) -- live through both phases
    bf16x8 qfh[2], qfl[2];
    #pragma unroll
    for (int dc = 0; dc < 2; ++dc) {
        size_t off = ((size_t)b * T_ + T0 + m16) * HD_ + dc * 32 + cho;
        qfh[dc] = *(const bf16x8*)(qhp + off);
        qfl[dc] = *(const bf16x8*)(qlp + off);
    }

    // ================= phase 1: full-row stats =================
    {
        const int colbase = wv * 256 + m16;            // wave covers 256 cols
        const short* kbh = khp + ((size_t)b * T_ + colbase) * HD_ + cho;
        const short* kbl = klp + ((size_t)b * T_ + colbase) * HD_ + cho;

        bf16x8 kfh[2][2], kfl[2][2];
        auto loadK = [&](int ct, bf16x8 kh[2], bf16x8 kl[2]) {
            #pragma unroll
            for (int dc = 0; dc < 2; ++dc) {
                kh[dc] = *(const bf16x8*)(kbh + (size_t)ct * 16 * HD_ + dc * 32);
                kl[dc] = *(const bf16x8*)(kbl + (size_t)ct * 16 * HD_ + dc * 32);
            }
        };
        loadK(0, kfh[0], kfl[0]);

        float ml[4], ll[4];
        #pragma unroll
        for (int r = 0; r < 4; ++r) { ml[r] = -1e30f; ll[r] = 0.f; }

        #pragma unroll
        for (int bq = 0; bq < 4; ++bq) {
            f32x4 sv[4];
            #pragma unroll
            for (int jj = 0; jj < 4; ++jj) {
                const int ct = bq * 4 + jj;
                const int cb = ct & 1;
                if (ct < 15) loadK(ct + 1, kfh[cb ^ 1], kfl[cb ^ 1]);
                f32x4 s = {0.f, 0.f, 0.f, 0.f};
                #pragma unroll
                for (int dc = 0; dc < 2; ++dc) {
                    s = MFMA_BF16(qfl[dc], kfh[cb][dc], s);
                    s = MFMA_BF16(qfh[dc], kfl[cb][dc], s);
                    s = MFMA_BF16(qfh[dc], kfh[cb][dc], s);
                }
                sv[jj] = s;
            }
            #pragma unroll
            for (int r = 0; r < 4; ++r) {
                float v0 = sv[0][r], v1 = sv[1][r], v2 = sv[2][r], v3 = sv[3][r];
                float mb = fmaxf(fmaxf(v0, v1), fmaxf(v2, v3));
                float lb = EXP2F(v0 - mb) + EXP2F(v1 - mb)
                         + EXP2F(v2 - mb) + EXP2F(v3 - mb);
                float mn = fmaxf(ml[r], mb);
                ll[r] = ll[r] * EXP2F(ml[r] - mn) + lb * EXP2F(mb - mn);
                ml[r] = mn;
            }
        }
        #pragma unroll
        for (int off = 1; off < 16; off <<= 1)
            #pragma unroll
            for (int r = 0; r < 4; ++r) {
                float mo = __shfl_xor(ml[r], off, 64);
                float lo = __shfl_xor(ll[r], off, 64);
                float mn = fmaxf(ml[r], mo);
                ll[r] = ll[r] * EXP2F(ml[r] - mn) + lo * EXP2F(mo - mn);
                ml[r] = mn;
            }
        if (m16 == 0) {
            #pragma unroll
            for (int r = 0; r < 4; ++r) {
                red[wv][q4 * 4 + r][0] = ml[r];
                red[wv][q4 * 4 + r][1] = ll[r];
            }
        }
    }
    __syncthreads();
    if (t < 16) {
        float M = red[0][t][0], S = red[0][t][1];
        #pragma unroll
        for (int w = 1; w < 8; ++w) {
            float mo = red[w][t][0], lo = red[w][t][1];
            float mn = fmaxf(M, mo);
            S = S * EXP2F(M - mn) + lo * EXP2F(mo - mn);
            M = mn;
        }
        msl[t] = M + __log2f(S);      // w1 = 2^(s - msl)
    }
    __syncthreads();

    // ============ phase 2: causal 2nd softmax + PV (recompute) ============
    const int CE = T0 + 16;           // causal col extent (multiple of 16)
    const int nC = (CE + 255) >> 8;   // 256-col chunks
    const int dt = wv & 3, chal = wv >> 2;   // step-B d-tile / col-half

    f32x4 ov = {0.f, 0.f, 0.f, 0.f};
    float dn = 0.f;
    const short* vrow = vtp + (size_t)b * 64 * T_ + (size_t)(dt * 16 + m16) * T_;

    for (int cc = 0; cc < nC; ++cc) {
        // ---- step A: QK^T recompute + weight + es write (tiles wv, wv+8)
        {
            const int ct0 = cc * 16 + wv;        // -> half 0, local col wv*16+m16
            const int ct1 = ct0 + 8;             // -> half 1
            const bool a0 = ct0 * 16 < CE, a1 = ct1 * 16 < CE;
            bf16x8 k0h[2], k0l[2], k1h[2], k1l[2];
            if (a0) {
                const short* ph = khp + ((size_t)b * T_ + ct0 * 16 + m16) * HD_ + cho;
                const short* pl = klp + ((size_t)b * T_ + ct0 * 16 + m16) * HD_ + cho;
                k0h[0] = *(const bf16x8*)ph;        k0h[1] = *(const bf16x8*)(ph + 32);
                k0l[0] = *(const bf16x8*)pl;        k0l[1] = *(const bf16x8*)(pl + 32);
            }
            if (a1) {
                const short* ph = khp + ((size_t)b * T_ + ct1 * 16 + m16) * HD_ + cho;
                const short* pl = klp + ((size_t)b * T_ + ct1 * 16 + m16) * HD_ + cho;
                k1h[0] = *(const bf16x8*)ph;        k1h[1] = *(const bf16x8*)(ph + 32);
                k1l[0] = *(const bf16x8*)pl;        k1l[1] = *(const bf16x8*)(pl + 32);
            }
            float e0[4] = {0.f, 0.f, 0.f, 0.f}, e1[4] = {0.f, 0.f, 0.f, 0.f};
            if (a0) {
                f32x4 s = {0.f, 0.f, 0.f, 0.f};
                #pragma unroll
                for (int dc = 0; dc < 2; ++dc) {
                    s = MFMA_BF16(qfl[dc], k0h[dc], s);
                    s = MFMA_BF16(qfh[dc], k0l[dc], s);
                    s = MFMA_BF16(qfh[dc], k0h[dc], s);
                }
                #pragma unroll
                for (int r = 0; r < 4; ++r) {
                    int colg = ct0 * 16 + m16, rowg = T0 + q4 * 4 + r;
                    float pvv = EXP2F(s[r] - msl[q4 * 4 + r]);
                    e0[r] = (colg <= rowg) ? __expf(pvv) : 0.f;
                }
            }
            if (a1) {
                f32x4 s = {0.f, 0.f, 0.f, 0.f};
                #pragma unroll
                for (int dc = 0; dc < 2; ++dc) {
                    s = MFMA_BF16(qfl[dc], k1h[dc], s);
                    s = MFMA_BF16(qfh[dc], k1l[dc], s);
                    s = MFMA_BF16(qfh[dc], k1h[dc], s);
                }
                #pragma unroll
                for (int r = 0; r < 4; ++r) {
                    int colg = ct1 * 16 + m16, rowg = T0 + q4 * 4 + r;
                    float pvv = EXP2F(s[r] - msl[q4 * 4 + r]);
                    e1[r] = (colg <= rowg) ? __expf(pvv) : 0.f;
                }
            }
            // es writes (zeros when tile skipped -> step B reads clean zeros)
            const int cl = wv * 16 + m16;                 // local col in half
            #pragma unroll
            for (int r = 0; r < 4; ++r) {
                int rw = q4 * 4 + r;
                int idx = (((cl >> 3) ^ rw) & 15) * 8 + (cl & 7);
                es[rw][0][idx] = e0[r];
                es[rw][1][idx] = e1[r];
            }
        }
        __syncthreads();
        // ---- step B: PV from es (wave: d-tile dt, col-half chal)
        {
            const int cbase = cc * 256 + chal * 128;
            #pragma unroll
            for (int sub = 0; sub < 4; ++sub) {
                int chunk = ((sub * 4 + q4) ^ m16) & 15;
                const float* ep = &es[m16][chal][chunk * 8];
                float4 x0 = *(const float4*)ep;
                float4 x1 = *(const float4*)(ep + 4);
                float ev[8] = {x0.x, x0.y, x0.z, x0.w, x1.x, x1.y, x1.z, x1.w};
                bf16x8 pf;
                #pragma unroll
                for (int e = 0; e < 8; ++e) {
                    dn += ev[e];
                    pf[e] = f2bf(ev[e]);
                }
                bf16x8 vf = *(const bf16x8*)(vrow + cbase + sub * 32 + q4 * 8);
                ov = MFMA_BF16(pf, vf, ov);
            }
        }
        __syncthreads();
    }

    // dn: lanes L, L^16, L^32, L^48 share row m16. All 4 waves of a half
    // compute the same row sums -> only the dt==0 wave contributes.
    dn += __shfl_xor(dn, 16, 64);
    dn += __shfl_xor(dn, 32, 64);
    if (dt == 0 && L < 16) dred[chal][L] = dn;
    #pragma unroll
    for (int r = 0; r < 4; ++r)
        ored2[wv][q4 * 4 + r][m16] = ov[r];   // wave's 16x16 d-tile
    __syncthreads();

    // 512 threads -> 16 rows x 64 d, float2 per thread, coalesced
    const int orow = t >> 5, d0 = (t & 31) * 2;
    float D = dred[0][orow] + dred[1][orow];
    float di = 1.f / D;
    const int dti = d0 >> 4;
    float o0 = ored2[dti][orow][d0 & 15]       + ored2[dti + 4][orow][d0 & 15];
    float o1 = ored2[dti][orow][(d0 + 1) & 15] + ored2[dti + 4][orow][(d0 + 1) & 15];
    float2 o = make_float2(o0 * di, o1 * di);
    *(float2*)(out + ((size_t)b * T_ + T0 + orow) * HD_ + d0) = o;
}

// ---------------------------------------------------------------------------
extern "C" void kernel_launch(void* const* d_in, const int* in_sizes, int n_in,
                              void* d_out, int out_size, void* d_ws, size_t ws_size,
                              hipStream_t stream) {
    (void)in_sizes; (void)n_in; (void)out_size; (void)ws_size;
    const float* x  = (const float*)d_in[0];
    const float* Wq = (const float*)d_in[1];
    const float* Wk = (const float*)d_in[2];
    const float* Wv = (const float*)d_in[3];
    float* outp = (float*)d_out;

    // ws layout:
    //   [0, 768K)        wt   (W fragment buffer; dead after proj)
    //   [768K, 5.75M)    qh/ql/kh/kl/vt   (no score buffer anymore)
    char* ws = (char*)d_ws;
    short* wt  = (short*)ws;
    short* qh = (short*)(ws + 786432);
    short* ql = (short*)(ws + 786432 + 1048576);
    short* kh = (short*)(ws + 786432 + 2 * 1048576);
    short* kl = (short*)(ws + 786432 + 3 * 1048576);
    short* vt = (short*)(ws + 786432 + 4 * 1048576);

    prep_w_kernel<<<dim3(16, 3), 256, 0, stream>>>(Wq, Wk, Wv, wt);
    qkv_proj_kernel<<<dim3(512), 256, 0, stream>>>(x, wt, qh, ql, kh, kl, vt);
    fused_attn_kernel<<<dim3(512), 512, 0, stream>>>(qh, ql, kh, kl, vt, outp);
}

// Round 12
// 141.848 us; speedup vs baseline: 1.1799x; 1.1799x over previous
//
#include <hip/hip_runtime.h>
#include <math.h>

#define T_  2048
#define C_  1024
#define HD_ 64

typedef __attribute__((ext_vector_type(8))) short bf16x8;   // 8 bf16 = 4 VGPRs
typedef __attribute__((ext_vector_type(4))) float f32x4;    // MFMA C/D

#define MFMA_BF16(A, B, C) __builtin_amdgcn_mfma_f32_16x16x32_bf16(A, B, C, 0, 0, 0)

// 8 * log2(e): q is pre-scaled so scores live in log2 domain (v_exp_f32 = 2^x)
#define QSCALE 11.54156032711171f

// v_exp_f32 is natively 2^x; HIP has no __exp2f device intrinsic (R5 compile fail)
#define EXP2F(x) __builtin_amdgcn_exp2f(x)

__device__ __forceinline__ short f2bf(float f) {
    union { float f; unsigned u; } v; v.f = f;
    unsigned r = v.u + 0x7fffu + ((v.u >> 16) & 1u);   // RTNE
    return (short)(r >> 16);
}
__device__ __forceinline__ float bf2f(short s) {
    union { float f; unsigned u; } v;
    v.u = ((unsigned)(unsigned short)s) << 16;
    return v.f;
}

// ---------------------------------------------------------------------------
// K0: W[1024][64] fp32 -> wtf in MFMA B-FRAGMENT order (hi/lo planes).
// ---------------------------------------------------------------------------
__global__ __launch_bounds__(256) void prep_w_kernel(
    const float* __restrict__ Wq, const float* __restrict__ Wk,
    const float* __restrict__ Wv, short* __restrict__ wtf)
{
    const int m = blockIdx.y;
    const float* W = (m == 0) ? Wq : (m == 1) ? Wk : Wv;
    const int t = threadIdx.x;
    const int c = blockIdx.x * 64 + (t >> 2);
    const int hg = (t & 3) * 16;
    const int ct = m * 4 + (t & 3);
    const int c0i = c >> 6, kc = (c >> 5) & 1, lq = (c >> 3) & 3, e = c & 7;
    const float4* wp = (const float4*)(W + (size_t)c * HD_ + hg);
    #pragma unroll
    for (int u = 0; u < 4; ++u) {
        float4 f = wp[u];
        float vs[4] = {f.x, f.y, f.z, f.w};
        #pragma unroll
        for (int ei = 0; ei < 4; ++ei) {
            int h16 = u * 4 + ei;              // h & 15
            int L = h16 + 16 * lq;
            short hh = f2bf(vs[ei]);
            short lo = f2bf(vs[ei] - bf2f(hh));
            size_t oh = ((((size_t)(ct * 2 + 0) * 16 + c0i) * 2 + kc) * 64 + L) * 8 + e;
            size_t ol = ((((size_t)(ct * 2 + 1) * 16 + c0i) * 2 + kc) * 64 + L) * 8 + e;
            wtf[oh] = hh;
            wtf[ol] = lo;
        }
    }
}

// ---------------------------------------------------------------------------
// K1: merged QKV projection (R3/R7-proven: 512 blocks x 256 thr, 2/CU,
// double-buffered x LDS, one barrier per step, W direct fragment loads).
// ---------------------------------------------------------------------------
__global__ __launch_bounds__(256) void qkv_proj_kernel(
    const float* __restrict__ x, const short* __restrict__ wtf,
    short* __restrict__ qhp, short* __restrict__ qlp,
    short* __restrict__ khp, short* __restrict__ klp,
    short* __restrict__ vtp)
{
    __shared__ __align__(16) short xh[2][16 * 64], xl[2][16 * 64];  // 2x2 KB each

    const int t = threadIdx.x, L = t & 63, wv = t >> 6;
    const int R0 = blockIdx.x * 16;
    const int ctq = wv;                    // wave's 16-col tile

    f32x4 acc[3];
    #pragma unroll
    for (int j = 0; j < 3; ++j) acc[j] = {0.f, 0.f, 0.f, 0.f};

    const int xrow = t >> 4, xc4 = t & 15;
    const float* xp = x + (size_t)(R0 + xrow) * C_ + xc4 * 4;
    float4 xa;
    auto loadX = [&](int c0) { xa = *(const float4*)(xp + c0); };

    const int c8 = xc4 >> 1, xhalf = xc4 & 1;
    const int slot = xrow * 64 + ((c8 ^ (xrow & 7)) * 8) + xhalf * 4;
    auto stageX = [&](int buf) {
        float vs[4] = {xa.x, xa.y, xa.z, xa.w};
        short4 vh, vl;
        short* vhp = (short*)&vh; short* vlp = (short*)&vl;
        #pragma unroll
        for (int e = 0; e < 4; ++e) {
            short hh = f2bf(vs[e]);
            vhp[e] = hh;
            vlp[e] = f2bf(vs[e] - bf2f(hh));
        }
        *(short4*)&xh[buf][slot] = vh;
        *(short4*)&xl[buf][slot] = vl;
    };

    const size_t lo8 = (size_t)L * 8;
    auto loadWF = [&](int c0i, int kc, bf16x8* w) {
        w[0] = *(const bf16x8*)(wtf + (size_t)((((ctq + 0) * 2 + 0) * 16 + c0i) * 2 + kc) * 512 + lo8);
        w[1] = *(const bf16x8*)(wtf + (size_t)((((ctq + 0) * 2 + 1) * 16 + c0i) * 2 + kc) * 512 + lo8);
        w[2] = *(const bf16x8*)(wtf + (size_t)((((ctq + 4) * 2 + 0) * 16 + c0i) * 2 + kc) * 512 + lo8);
        w[3] = *(const bf16x8*)(wtf + (size_t)((((ctq + 4) * 2 + 1) * 16 + c0i) * 2 + kc) * 512 + lo8);
        w[4] = *(const bf16x8*)(wtf + (size_t)((((ctq + 8) * 2 + 0) * 16 + c0i) * 2 + kc) * 512 + lo8);
    };

    bf16x8 wf0[5], wf1[5];
    const int arow = L & 15;

    loadX(0);
    loadWF(0, 0, wf0);
    stageX(0);
    loadX(64);
    __syncthreads();

    for (int c0i = 0; c0i < 16; ++c0i) {
        const int cur = c0i & 1;
        if (c0i < 15) {
            stageX(cur ^ 1);
            if (c0i < 14) loadX((c0i + 2) * 64);
        }
        loadWF(c0i, 1, wf1);
        {
            int ch = (L >> 4);
            int off = arow * 64 + ((ch ^ (arow & 7)) * 8);
            bf16x8 axh = *(const bf16x8*)&xh[cur][off];
            bf16x8 axl = *(const bf16x8*)&xl[cur][off];
            acc[0] = MFMA_BF16(axl, wf0[0], acc[0]);
            acc[0] = MFMA_BF16(axh, wf0[1], acc[0]);
            acc[0] = MFMA_BF16(axh, wf0[0], acc[0]);
            acc[1] = MFMA_BF16(axl, wf0[2], acc[1]);
            acc[1] = MFMA_BF16(axh, wf0[3], acc[1]);
            acc[1] = MFMA_BF16(axh, wf0[2], acc[1]);
            acc[2] = MFMA_BF16(wf0[4], axh, acc[2]);   // v swapped -> D[h][t]
        }
        if (c0i < 15) loadWF(c0i + 1, 0, wf0);
        {
            int ch = 4 + (L >> 4);
            int off = arow * 64 + ((ch ^ (arow & 7)) * 8);
            bf16x8 axh = *(const bf16x8*)&xh[cur][off];
            bf16x8 axl = *(const bf16x8*)&xl[cur][off];
            acc[0] = MFMA_BF16(axl, wf1[0], acc[0]);
            acc[0] = MFMA_BF16(axh, wf1[1], acc[0]);
            acc[0] = MFMA_BF16(axh, wf1[0], acc[0]);
            acc[1] = MFMA_BF16(axl, wf1[2], acc[1]);
            acc[1] = MFMA_BF16(axh, wf1[3], acc[1]);
            acc[1] = MFMA_BF16(axh, wf1[2], acc[1]);
            acc[2] = MFMA_BF16(wf1[4], axh, acc[2]);
        }
        __syncthreads();
    }

    // ---- epilogue (q scaled into log2 domain: 8*log2(e))
    const int quad = L >> 4;
    #pragma unroll
    for (int r = 0; r < 4; ++r) {
        int row = R0 + quad * 4 + r;
        int h = ctq * 16 + (L & 15);
        float vq = acc[0][r] * QSCALE;
        short hq = f2bf(vq);
        qhp[(size_t)row * HD_ + h] = hq;
        qlp[(size_t)row * HD_ + h] = f2bf(vq - bf2f(hq));
        float vk = acc[1][r];
        short hk = f2bf(vk);
        khp[(size_t)row * HD_ + h] = hk;
        klp[(size_t)row * HD_ + h] = f2bf(vk - bf2f(hk));
        int d = ctq * 16 + quad * 4 + r;
        int tt = R0 + (L & 15);
        int bb = tt >> 11, tl = tt & (T_ - 1);
        vtp[(size_t)(bb * 64 + d) * T_ + tl] = f2bf(acc[2][r]);
    }
}

// ---------------------------------------------------------------------------
// K2a: stats + causal score spill. REDESIGNED for occupancy: 32-row blocks,
// 128-col segments, grid (64,16,4) = 4096 blocks. Register state ~100 VGPR
// (qf 32 + ml/ll 16 + kf 32) -> 4 waves/SIMD tier (R7's 64-row/sv version
// was ~180 VGPR -> 2 waves/SIMD). Online (m,l) update; exp2 domain.
// pm is row-major: pm[((b*T + row)*16 + seg)*2] = {m, l}.
// ---------------------------------------------------------------------------
__global__ __launch_bounds__(256) void stats_kernel(
    const short* __restrict__ qhp, const short* __restrict__ qlp,
    const short* __restrict__ khp, const short* __restrict__ klp,
    float* __restrict__ pm, float* __restrict__ sc)
{
    __shared__ float red[4 * 32 * 2];

    const int t = threadIdx.x, L = t & 63, wv = t >> 6;
    const int bt = blockIdx.x, seg = blockIdx.y, b = blockIdx.z;
    const int R0 = bt * 32, S0 = seg * 128;

    bf16x8 qfh[2][2], qfl[2][2];
    #pragma unroll
    for (int rt = 0; rt < 2; ++rt)
        #pragma unroll
        for (int dc = 0; dc < 2; ++dc) {
            int row = R0 + rt * 16 + (L & 15);
            size_t off = ((size_t)b * T_ + row) * HD_ + dc * 32 + (L >> 4) * 8;
            qfh[rt][dc] = *(const bf16x8*)(qhp + off);
            qfl[rt][dc] = *(const bf16x8*)(qlp + off);
        }

    float ml[2][4], ll[2][4];
    #pragma unroll
    for (int rt = 0; rt < 2; ++rt)
        #pragma unroll
        for (int r = 0; r < 4; ++r) { ml[rt][r] = -1e30f; ll[rt][r] = 0.f; }

    const int colL = wv * 16 + (L & 15);
    const short* kbh = khp + ((size_t)b * T_ + S0 + colL) * HD_;
    const short* kbl = klp + ((size_t)b * T_ + S0 + colL) * HD_;
    const int cho = (L >> 4) * 8;

    bf16x8 kfh[2][2], kfl[2][2];
    auto loadK = [&](int jt, bf16x8 kh[2], bf16x8 kl[2]) {
        #pragma unroll
        for (int dc = 0; dc < 2; ++dc) {
            kh[dc] = *(const bf16x8*)(kbh + (size_t)jt * 64 * HD_ + dc * 32 + cho);
            kl[dc] = *(const bf16x8*)(kbl + (size_t)jt * 64 * HD_ + dc * 32 + cho);
        }
    };
    loadK(0, kfh[0], kfl[0]);

    #pragma unroll
    for (int jt = 0; jt < 2; ++jt) {
        if (jt < 1) loadK(1, kfh[1], kfl[1]);
        const bool doStore = (S0 + jt * 64) <= (R0 + 31);   // causal-needed tile
        #pragma unroll
        for (int rt = 0; rt < 2; ++rt) {
            f32x4 s = {0.f, 0.f, 0.f, 0.f};
            #pragma unroll
            for (int dc = 0; dc < 2; ++dc) {
                s = MFMA_BF16(qfl[rt][dc], kfh[jt][dc], s);
                s = MFMA_BF16(qfh[rt][dc], kfl[jt][dc], s);
                s = MFMA_BF16(qfh[rt][dc], kfh[jt][dc], s);
            }
            if (doStore) {
                #pragma unroll
                for (int r = 0; r < 4; ++r) {
                    int row = R0 + rt * 16 + (L >> 4) * 4 + r;
                    sc[((size_t)b * T_ + row) * T_ + S0 + jt * 64 + colL] = s[r];
                }
            }
            #pragma unroll
            for (int r = 0; r < 4; ++r) {
                float mn = fmaxf(ml[rt][r], s[r]);
                ll[rt][r] = ll[rt][r] * EXP2F(ml[rt][r] - mn) + EXP2F(s[r] - mn);
                ml[rt][r] = mn;
            }
        }
    }
    // merge the 16 columns within each wave
    #pragma unroll
    for (int off = 1; off < 16; off <<= 1)
        #pragma unroll
        for (int rt = 0; rt < 2; ++rt)
            #pragma unroll
            for (int r = 0; r < 4; ++r) {
                float mo = __shfl_xor(ml[rt][r], off, 64);
                float lo = __shfl_xor(ll[rt][r], off, 64);
                float mn = fmaxf(ml[rt][r], mo);
                ll[rt][r] = ll[rt][r] * EXP2F(ml[rt][r] - mn) + lo * EXP2F(mo - mn);
                ml[rt][r] = mn;
            }
    if ((L & 15) == 0) {
        #pragma unroll
        for (int rt = 0; rt < 2; ++rt)
            #pragma unroll
            for (int r = 0; r < 4; ++r) {
                int row = rt * 16 + (L >> 4) * 4 + r;
                red[(wv * 32 + row) * 2 + 0] = ml[rt][r];
                red[(wv * 32 + row) * 2 + 1] = ll[rt][r];
            }
    }
    __syncthreads();
    if (t < 32) {
        float M = red[t * 2], S = red[t * 2 + 1];
        #pragma unroll
        for (int w = 1; w < 4; ++w) {
            float mo = red[(w * 32 + t) * 2], lo = red[(w * 32 + t) * 2 + 1];
            float mn = fmaxf(M, mo);
            S = S * EXP2F(M - mn) + lo * EXP2F(mo - mn);
            M = mn;
        }
        size_t o = (((size_t)b * T_ + R0 + t) * 16 + seg) * 2;
        pm[o] = M;
        pm[o + 1] = S;
    }
}

// ---------------------------------------------------------------------------
// K2c: causal second softmax + PV (R7-proven), streaming spilled scores with
// a 2-deep register pipeline; stat_merge folded (now 16 segments, row-major
// pm). Block pairs (p, 127-p) balance pv lengths per CU.
// ---------------------------------------------------------------------------
__global__ __launch_bounds__(256) void pv_kernel(
    const float* __restrict__ sc, const short* __restrict__ vtp,
    const float* __restrict__ pm, float* __restrict__ out)
{
    __shared__ float ored[4][16][64];   // 16 KB: per-wave PV partials
    __shared__ float dred[4][16];
    __shared__ float msl[16];

    const int t = threadIdx.x, L = t & 63, wv = t >> 6;
    const int b = blockIdx.x & 3;
    const int i = blockIdx.x >> 2;
    const int p = (i < 64) ? (127 - i) : (i - 64);
    const int T0 = p * 16;

    if (t < 16) {                       // folded stat_merge for these 16 rows
        int row = T0 + t;
        float M = -1e30f, S = 0.f;
        #pragma unroll
        for (int seg = 0; seg < 16; ++seg) {
            size_t o = (((size_t)b * T_ + row) * 16 + seg) * 2;
            float mo = pm[o], lo = pm[o + 1];
            float mn = fmaxf(M, mo);
            S = S * EXP2F(M - mn) + lo * EXP2F(mo - mn);
            M = mn;
        }
        msl[t] = M + __log2f(S);        // w = 2^(s2 - msl)
    }
    __syncthreads();

    const int row = T0 + (L & 15);
    const float mls = msl[L & 15];
    const float* srow = sc + ((size_t)b * T_ + row) * T_;
    const short* vb = vtp + (size_t)b * 64 * T_;
    const int nJ = (T0 + 143) >> 7;     // ceil((T0+16)/128)
    const int cq = (L >> 4) * 8;

    f32x4 ov[4];
    #pragma unroll
    for (int dt = 0; dt < 4; ++dt) ov[dt] = {0.f, 0.f, 0.f, 0.f};
    float dn = 0.f;

    float4 sa0, sa1, sb0, sb1;
    bf16x8 va0, va1, va2, va3, vb0, vb1, vb2, vb3;

#define LDS_(jt, s0, s1) { int c0_ = (jt) * 128 + wv * 32 + cq;                  \
        s0 = *(const float4*)(srow + c0_); s1 = *(const float4*)(srow + c0_ + 4); }
#define LDV_(jt, v0, v1, v2, v3) { int c0_ = (jt) * 128 + wv * 32 + cq;          \
        v0 = *(const bf16x8*)(vb + (size_t)( 0 + (L & 15)) * T_ + c0_);          \
        v1 = *(const bf16x8*)(vb + (size_t)(16 + (L & 15)) * T_ + c0_);          \
        v2 = *(const bf16x8*)(vb + (size_t)(32 + (L & 15)) * T_ + c0_);          \
        v3 = *(const bf16x8*)(vb + (size_t)(48 + (L & 15)) * T_ + c0_); }
#define BODY_(jt, s0, s1, v0, v1, v2, v3) {                                      \
        const int c0_ = (jt) * 128 + wv * 32 + cq;                               \
        float vs_[8] = {s0.x, s0.y, s0.z, s0.w, s1.x, s1.y, s1.z, s1.w};         \
        bf16x8 ef_;                                                              \
        _Pragma("unroll")                                                        \
        for (int e = 0; e < 8; ++e) {                                            \
            float pvv = EXP2F(vs_[e] - mls);                                     \
            float evv = (c0_ + e <= row) ? __expf(pvv) : 0.f;                    \
            dn += evv;                                                           \
            ef_[e] = f2bf(evv);                                                  \
        }                                                                        \
        ov[0] = MFMA_BF16(ef_, v0, ov[0]);                                       \
        ov[1] = MFMA_BF16(ef_, v1, ov[1]);                                       \
        ov[2] = MFMA_BF16(ef_, v2, ov[2]);                                       \
        ov[3] = MFMA_BF16(ef_, v3, ov[3]); }

    LDS_(0, sa0, sa1)
    LDV_(0, va0, va1, va2, va3)
    int jt = 0;
    for (; jt + 2 <= nJ; jt += 2) {
        LDS_(jt + 1, sb0, sb1)
        LDV_(jt + 1, vb0, vb1, vb2, vb3)
        BODY_(jt, sa0, sa1, va0, va1, va2, va3)
        if (jt + 2 < nJ) {
            LDS_(jt + 2, sa0, sa1)
            LDV_(jt + 2, va0, va1, va2, va3)
        }
        BODY_(jt + 1, sb0, sb1, vb0, vb1, vb2, vb3)
    }
    if (jt < nJ) {
        BODY_(jt, sa0, sa1, va0, va1, va2, va3)
    }
#undef LDS_
#undef LDV_
#undef BODY_

    dn += __shfl_xor(dn, 16, 64);
    dn += __shfl_xor(dn, 32, 64);
    if (L < 16) dred[wv][L] = dn;
    #pragma unroll
    for (int dt = 0; dt < 4; ++dt)
        #pragma unroll
        for (int r = 0; r < 4; ++r)
            ored[wv][(L >> 4) * 4 + r][dt * 16 + (L & 15)] = ov[dt][r];
    __syncthreads();

    const int orow = t >> 4, d0 = (t & 15) * 4;
    float D = dred[0][orow] + dred[1][orow] + dred[2][orow] + dred[3][orow];
    float di = 1.f / D;
    float4 o;
    o.x = (ored[0][orow][d0 + 0] + ored[1][orow][d0 + 0]
         + ored[2][orow][d0 + 0] + ored[3][orow][d0 + 0]) * di;
    o.y = (ored[0][orow][d0 + 1] + ored[1][orow][d0 + 1]
         + ored[2][orow][d0 + 1] + ored[3][orow][d0 + 1]) * di;
    o.z = (ored[0][orow][d0 + 2] + ored[1][orow][d0 + 2]
         + ored[2][orow][d0 + 2] + ored[3][orow][d0 + 2]) * di;
    o.w = (ored[0][orow][d0 + 3] + ored[1][orow][d0 + 3]
         + ored[2][orow][d0 + 3] + ored[3][orow][d0 + 3]) * di;
    *(float4*)(out + ((size_t)b * T_ + T0 + orow) * HD_ + d0) = o;
}

// ---------------------------------------------------------------------------
extern "C" void kernel_launch(void* const* d_in, const int* in_sizes, int n_in,
                              void* d_out, int out_size, void* d_ws, size_t ws_size,
                              hipStream_t stream) {
    (void)in_sizes; (void)n_in; (void)out_size; (void)ws_size;
    const float* x  = (const float*)d_in[0];
    const float* Wq = (const float*)d_in[1];
    const float* Wk = (const float*)d_in[2];
    const float* Wv = (const float*)d_in[3];
    float* outp = (float*)d_out;

    // ws layout:
    //   [0, 768K)        wt   (W fragment buffer; dead after proj)
    //   [768K, 5.75M)    qh/ql/kh/kl/vt
    //   [8M, 72M)        sc   scores f32 [4][2048][2048]
    //   [72M, 74M)       pm   stats partials [4][2048][16][2] f32
    char* ws = (char*)d_ws;
    short* wt  = (short*)ws;
    short* qh = (short*)(ws + 786432);
    short* ql = (short*)(ws + 786432 + 1048576);
    short* kh = (short*)(ws + 786432 + 2 * 1048576);
    short* kl = (short*)(ws + 786432 + 3 * 1048576);
    short* vt = (short*)(ws + 786432 + 4 * 1048576);
    float* sc = (float*)(ws + 8388608);
    float* pm = (float*)(ws + 75497472);

    prep_w_kernel<<<dim3(16, 3), 256, 0, stream>>>(Wq, Wk, Wv, wt);
    qkv_proj_kernel<<<dim3(512), 256, 0, stream>>>(x, wt, qh, ql, kh, kl, vt);
    stats_kernel<<<dim3(64, 16, 4), 256, 0, stream>>>(qh, ql, kh, kl, pm, sc);
    pv_kernel<<<dim3(512), 256, 0, stream>>>(sc, vt, pm, outp);
}